// Round 5
// baseline (2490.978 us; speedup 1.0000x reference)
//
#include <hip/hip_runtime.h>
#include <math.h>

// ---------------- problem constants ----------------
#define TDIM  100
#define HIDN  100
#define G3    300
#define WD    132
#define CIP   104      // padded ci pitch (multiple of 8)
#define KP    1056     // padded conv K = 10*104 -> 33 ksteps of 32
#define NKC   33
#define GIK   17440    // padded FEAT (17424 -> 545 ksteps of 32)
#define GIN   320      // padded 3*HID
#define BTOT  16
#define BCH   4        // batches per conv chunk (R3-proven live-set size)
#define INP0  (159 * WD)   // 20988

typedef float    f32x4 __attribute__((ext_vector_type(4)));
typedef _Float16 f16x8 __attribute__((ext_vector_type(8)));
typedef _Float16 f16x4 __attribute__((ext_vector_type(4)));

static __device__ __forceinline__ float sigmoidf_(float x) {
    return 1.f / (1.f + __expf(-x));
}
static __device__ __forceinline__ float bcastf(float v, int l) {
    return __int_as_float(__builtin_amdgcn_readlane(__float_as_int(v), l));
}

// ---------------- weight prepack: w[co][ci][kh] -> wp[112][KP], k = kh*104+ci ----------------
__global__ __launch_bounds__(256)
void prep_convw(const float* __restrict__ w, _Float16* __restrict__ wp)
{
    const int idx = blockIdx.x * 256 + threadIdx.x;
    if (idx >= 112 * KP) return;
    const int co = idx / KP, k = idx - co * KP;
    const int kh = k / CIP, ci = k - kh * CIP;
    float v = 0.f;
    if (co < 100 && ci < 100 && kh < 10)
        v = w[(co * 100 + ci) * 10 + kh];
    wp[idx] = (_Float16)v;
}

// ---------------- w_ih prepack: [300][17424] -> [GIN][GIK] fp16, zero pad ----------------
__global__ __launch_bounds__(256)
void prep_wih(const float* __restrict__ w_ih, _Float16* __restrict__ wihp)
{
    const int k = blockIdx.x * 256 + threadIdx.x;
    const int n = blockIdx.y;
    if (k >= GIK) return;
    const float v = (n < G3 && k < 17424) ? w_ih[(size_t)n * 17424 + k] : 0.f;
    wihp[(size_t)n * GIK + k] = (_Float16)v;
}

// ---------------- x transpose: x[b][ci][p] fp32 -> xT[b][p][CIP] fp16 (pad ci zeroed) -------
__global__ __launch_bounds__(256)
void transpose_x(const float* __restrict__ x, _Float16* __restrict__ xT)
{
    __shared__ __align__(16) _Float16 t[64][116];
    const int tid = threadIdx.x;
    const int p0  = blockIdx.x * 64;
    const int b   = blockIdx.y;
    const int pl  = tid & 63;
    const int p   = p0 + pl;
    t[tid >> 2][100 + (tid & 3)] = (_Float16)0.f;   // zero ci pad (finite!)
    const float* xb = x + (size_t)b * 100 * INP0;
    #pragma unroll
    for (int i = 0; i < 25; ++i) {
        const int ci = (tid >> 6) + i * 4;
        const float v = (p < INP0) ? xb[(size_t)ci * INP0 + p] : 0.f;
        t[pl][ci] = (_Float16)v;
    }
    __syncthreads();
    _Float16* xTb = xT + (size_t)b * INP0 * CIP;
    #pragma unroll
    for (int i = 0; i < 7; ++i) {
        const int idx = tid + i * 256;
        if (idx < 64 * 26) {
            const int rr = idx / 26;
            const int c  = (idx - rr * 26) * 4;
            if (p0 + rr < INP0)
                *(f16x4*)(xTb + (size_t)(p0 + rr) * CIP + c) = *(const f16x4*)&t[rr][c];
        }
    }
}

// ---------------- conv as MFMA GEMM (pipelined k-loop + LDS-staged coalesced epilogue) ------
// C[co,p] = bias[co] + sum_k wp[co][k] * actT[p + kh*132][ci],  k = kh*104+ci
// Tiles: M=112 (7x16), N=256 (16x16); wave w owns n-tiles 4w..4w+3.
// Epilogue: acc -> LDS tile (2 passes of 128 p) -> fully coalesced uint4 stores.
template<int HIN, bool OUTT>
__global__ __launch_bounds__(256)
void conv_mfma(const _Float16* __restrict__ actT,   // [BCH][HIN*132][CIP]
               const _Float16* __restrict__ wp,     // [112][KP]
               const float*    __restrict__ bias,   // [100]
               _Float16* __restrict__ out)
{
    constexpr int HOUT = HIN - 9;
    constexpr int NP   = HOUT * WD;
    constexpr int INP  = HIN * WD;

    // one smem pool: k-loop uses As[112][40] + Bs[256][40] = 14720 f16;
    // epilogue reuses it as [128][112] (OUTT) or [104][136] (gi path).
    __shared__ __align__(16) _Float16 smem[368 * 40];
    _Float16 (*As)[40] = (_Float16(*)[40])smem;
    _Float16 (*Bs)[40] = (_Float16(*)[40])(smem + 112 * 40);

    // XCD-aware swizzle: blocks with equal (flat%8) get a contiguous work range,
    // so adjacent p-tiles (~83% shared input rows) share one XCD's L2.
    const int nbx = gridDim.x;
    int g = blockIdx.y * nbx + blockIdx.x;
    const int per = (nbx * gridDim.y) >> 3;       // grids are padded to %8==0
    g = (g & 7) * per + (g >> 3);
    const int px = g % nbx;
    const int b  = g / nbx;
    const int p0 = px * 256;
    if (p0 >= NP) return;                         // padded tail block

    const _Float16* act_b = actT + (size_t)b * INP * CIP;

    f32x4 acc[7][4] = {};
    const int tid = threadIdx.x;
    const int wv = tid >> 6, ln = tid & 15, lq = (tid & 63) >> 4;
    const int arow = tid >> 2;          // 0..63 granule row base
    const int run  = tid & 3;           // k-granule within 32-chunk

    uint4 ar[2], br[4];

    auto load_regs = [&](int kk) {
        const int k0 = kk * 32;
        const int k  = k0 + run * 8;
        const int kh = k / CIP;
        const int ci0 = k - kh * CIP;
        ar[0] = *(const uint4*)(wp + (size_t)arow * KP + k0 + run * 8);
        if (tid < 192)
            ar[1] = *(const uint4*)(wp + (size_t)(64 + arow) * KP + k0 + run * 8);
        const int rbase = p0 + kh * WD;
        #pragma unroll
        for (int i = 0; i < 4; ++i) {
            int row = rbase + arow + i * 64;
            row = min(row, INP - 1);     // clamped rows feed discarded cols only
            br[i] = *(const uint4*)(act_b + (size_t)row * CIP + ci0);
        }
    };

    load_regs(0);
    for (int kk = 0; kk < NKC; ++kk) {
        *(uint4*)&As[arow][run * 8] = ar[0];
        if (tid < 192) *(uint4*)&As[64 + arow][run * 8] = ar[1];
        #pragma unroll
        for (int i = 0; i < 4; ++i)
            *(uint4*)&Bs[arow + i * 64][run * 8] = br[i];
        __syncthreads();
        if (kk + 1 < NKC) load_regs(kk + 1);   // global loads overlap MFMA phase
        f16x8 bf[4];
        #pragma unroll
        for (int j = 0; j < 4; ++j)
            bf[j] = *(const f16x8*)&Bs[(wv * 4 + j) * 16 + ln][lq * 8];
        #pragma unroll
        for (int mt = 0; mt < 7; ++mt) {
            const f16x8 af = *(const f16x8*)&As[mt * 16 + ln][lq * 8];
            #pragma unroll
            for (int j = 0; j < 4; ++j)
                acc[mt][j] = __builtin_amdgcn_mfma_f32_16x16x32_f16(af, bf[j], acc[mt][j], 0, 0, 0);
        }
        __syncthreads();
    }

    // ---- LDS-staged epilogue: 2 passes of 128 p-rows ----
    const int wv2 = wv >> 1;
    #pragma unroll
    for (int ph = 0; ph < 2; ++ph) {
        __syncthreads();                 // smem free (k-loop / previous pass done)
        if (wv2 == ph) {                 // waves 2ph, 2ph+1 own p-rows of this pass
            #pragma unroll
            for (int j = 0; j < 4; ++j) {
                const int pl = (wv & 1) * 64 + j * 16 + ln;   // 0..127
                if (OUTT) {
                    _Float16* row = smem + pl * 112;          // pitch 112 (224 B, 16B-mult)
                    #pragma unroll
                    for (int mt = 0; mt < 7; ++mt) {
                        const int co0 = mt * 16 + lq * 4;
                        if (co0 < CIP) {
                            f16x4 v;
                            #pragma unroll
                            for (int r = 0; r < 4; ++r) {
                                const int co = co0 + r;
                                v[r] = (_Float16)(acc[mt][j][r] + (co < 100 ? bias[co] : 0.f));
                            }
                            *(f16x4*)(row + co0) = v;
                        }
                    }
                } else {
                    #pragma unroll
                    for (int mt = 0; mt < 7; ++mt) {
                        #pragma unroll
                        for (int r = 0; r < 4; ++r) {
                            const int co = mt * 16 + lq * 4 + r;
                            if (co < CIP)
                                smem[co * 136 + pl] =          // pitch 136 (272 B, 16B-mult)
                                    (_Float16)(acc[mt][j][r] + (co < 100 ? bias[co] : 0.f));
                        }
                    }
                }
            }
        }
        __syncthreads();
        if (OUTT) {
            // 128 rows x 208 B, fully contiguous across the block
            for (int i = tid; i < 128 * 13; i += 256) {
                const int r = i / 13, c = i - r * 13;
                const int p = p0 + ph * 128 + r;
                if (p < NP)
                    *(uint4*)(out + ((size_t)b * NP + p) * CIP + c * 8) =
                        *(const uint4*)(smem + r * 112 + c * 8);
            }
        } else {
            // 100 gi-rows x 256 B contiguous each (NP%8==0 -> all-or-nothing chunks)
            for (int i = tid; i < 100 * 16; i += 256) {
                const int r = i >> 4, c = i & 15;
                const int p = p0 + ph * 128 + c * 8;
                if (p < NP)
                    *(uint4*)(out + ((size_t)b * 100 + r) * GIK + p) =
                        *(const uint4*)(smem + r * 136 + c * 8);
            }
        }
    }
}

// ---------------- big GEMM: xw += gi @ wihp^T (128x128 tile, pipelined, z=26) --------------
// per chunk: A = gi [400][GIK], B = wihp [GIN][GIK], C = xw rows for the chunk
__global__ __launch_bounds__(256)
void gemm_mfma(const _Float16* __restrict__ A, const _Float16* __restrict__ B,
               float* __restrict__ C)
{
    constexpr int M   = BCH * TDIM;   // 400
    constexpr int NKG = GIK / 32;     // 545
    constexpr int ZS  = 26;
    constexpr int SEG = (NKG + ZS - 1) / ZS;   // 21

    __shared__ __align__(16) _Float16 As[128][40];
    __shared__ __align__(16) _Float16 Bs[128][40];

    const int tid = threadIdx.x;
    const int n0  = blockIdx.x * 128;
    const int m0  = blockIdx.y * 128;
    const int k00 = blockIdx.z * SEG;
    const int k01 = min(NKG, k00 + SEG);

    const int wv = tid >> 6, ln = tid & 15, lq = (tid & 63) >> 4;
    const int mh = wv >> 1, nh = wv & 1;
    const int grow = tid >> 2, run = tid & 3;

    f32x4 acc[4][4] = {};
    uint4 ar[2], br[2];

    auto load_regs = [&](int kk) {
        const int k0 = kk * 32;
        #pragma unroll
        for (int i = 0; i < 2; ++i) {
            const int ra = min(m0 + grow + i * 64, M - 1);
            const int rb = min(n0 + grow + i * 64, GIN - 1);
            ar[i] = *(const uint4*)(A + (size_t)ra * GIK + k0 + run * 8);
            br[i] = *(const uint4*)(B + (size_t)rb * GIK + k0 + run * 8);
        }
    };

    load_regs(k00);
    for (int kk = k00; kk < k01; ++kk) {
        #pragma unroll
        for (int i = 0; i < 2; ++i) {
            *(uint4*)&As[grow + i * 64][run * 8] = ar[i];
            *(uint4*)&Bs[grow + i * 64][run * 8] = br[i];
        }
        __syncthreads();
        if (kk + 1 < k01) load_regs(kk + 1);
        f16x8 af[4], bf[4];
        #pragma unroll
        for (int i = 0; i < 4; ++i) {
            af[i] = *(const f16x8*)&As[mh * 64 + i * 16 + ln][lq * 8];
            bf[i] = *(const f16x8*)&Bs[nh * 64 + i * 16 + ln][lq * 8];
        }
        #pragma unroll
        for (int mt = 0; mt < 4; ++mt)
            #pragma unroll
            for (int nt = 0; nt < 4; ++nt)
                acc[mt][nt] = __builtin_amdgcn_mfma_f32_16x16x32_f16(af[mt], bf[nt], acc[mt][nt], 0, 0, 0);
        __syncthreads();
    }

    #pragma unroll
    for (int mt = 0; mt < 4; ++mt) {
        #pragma unroll
        for (int nt = 0; nt < 4; ++nt) {
            const int n = n0 + nh * 64 + nt * 16 + ln;
            const int mb = m0 + mh * 64 + mt * 16 + lq * 4;
            if (n < G3) {
                #pragma unroll
                for (int rr = 0; rr < 4; ++rr) {
                    const int m = mb + rr;
                    if (m < M) atomicAdd(&C[(size_t)m * G3 + n], acc[mt][nt][rr]);
                }
            }
        }
    }
}

// ---------------- xw init: xw[row, g] = b_ih[g] ----------------
__global__ __launch_bounds__(256)
void init_xw_k(const float* __restrict__ b_ih, float* __restrict__ xw)
{
    const int i = blockIdx.x * 256 + threadIdx.x;
    if (i < BTOT * TDIM * G3) xw[i] = b_ih[i % G3];
}

// ---------------- GRU scan: prefetch xw via LDS, 4-way acc split ----------------
__global__ __launch_bounds__(320)
void gru_k(const float* __restrict__ xw, const float* __restrict__ w_hh,
           const float* __restrict__ b_hh, float* __restrict__ gout)
{
    __shared__ float h_s[128];
    __shared__ float gh_s[G3];
    __shared__ float xw_s[G3];

    const int tid = threadIdx.x;
    const int b   = blockIdx.x;
    const float* xw_b = xw + (size_t)b * TDIM * G3;

    const int rowc = (tid < G3) ? tid : (G3 - 1);
    const float bh = b_hh[rowc];
    float wreg[HIDN];
    #pragma unroll
    for (int k = 0; k < HIDN; ++k) wreg[k] = w_hh[(size_t)rowc * HIDN + k];

    if (tid < 128) h_s[tid] = 0.f;
    float xr = 0.f;
    if (tid < G3) xr = xw_b[tid];
    __syncthreads();

    const int lane = tid & 63;
    for (int t = 0; t < TDIM; ++t) {
        const float hlo = h_s[lane];          // full-exec snapshot (readlane hazard)
        const float hhi = h_s[64 + lane];
        if (tid < G3) xw_s[tid] = xr;
        float xr_n = 0.f;                      // prefetch next step: hide HBM latency
        if (tid < G3) xr_n = xw_b[(size_t)min(t + 1, TDIM - 1) * G3 + tid];
        float a0 = bh, a1 = 0.f, a2 = 0.f, a3 = 0.f;
        #pragma unroll
        for (int k = 0; k < 64; k += 4) {
            a0 += wreg[k + 0] * bcastf(hlo, k + 0);
            a1 += wreg[k + 1] * bcastf(hlo, k + 1);
            a2 += wreg[k + 2] * bcastf(hlo, k + 2);
            a3 += wreg[k + 3] * bcastf(hlo, k + 3);
        }
        #pragma unroll
        for (int k = 64; k < 100; k += 4) {
            a0 += wreg[k + 0] * bcastf(hhi, k - 64);
            a1 += wreg[k + 1] * bcastf(hhi, k - 63);
            a2 += wreg[k + 2] * bcastf(hhi, k - 62);
            a3 += wreg[k + 3] * bcastf(hhi, k - 61);
        }
        if (tid < G3) gh_s[tid] = (a0 + a1) + (a2 + a3);
        __syncthreads();
        if (tid < HIDN) {
            const float hp = h_s[tid];
            const float r  = sigmoidf_(xw_s[tid]            + gh_s[tid]);
            const float z  = sigmoidf_(xw_s[HIDN + tid]     + gh_s[HIDN + tid]);
            const float n  = tanhf(xw_s[2 * HIDN + tid] + r * gh_s[2 * HIDN + tid]);
            const float hn = (1.f - z) * n + z * hp;
            h_s[tid] = hn;
            gout[((size_t)b * TDIM + t) * HIDN + tid] = hn;
        }
        xr = xr_n;
        __syncthreads();
    }
}

// ---------------- output heads ----------------
__global__ __launch_bounds__(256)
void heads_k(const float* __restrict__ g,
             const float* __restrict__ wy1, const float* __restrict__ by1,
             const float* __restrict__ wy2, const float* __restrict__ by2,
             float* __restrict__ out)
{
    constexpr int NY1 = BTOT * TDIM * 14;
    constexpr int NY2 = BTOT * TDIM * 3;
    const int idx = blockIdx.x * 256 + threadIdx.x;
    if (idx < NY1) {
        const int row = idx / 14, c = idx - row * 14;
        const float* gr = g + (size_t)row * HIDN;
        const float* wr = wy1 + c * HIDN;
        float acc = by1[c];
        for (int k = 0; k < HIDN; ++k) acc += gr[k] * wr[k];
        out[idx] = sigmoidf_(acc);
    } else if (idx < NY1 + NY2) {
        const int j = idx - NY1;
        const int row = j / 3, c = j - row * 3;
        const float* gr = g + (size_t)row * HIDN;
        const float* wr = wy2 + c * HIDN;
        float acc = by2[c];
        for (int k = 0; k < HIDN; ++k) acc += gr[k] * wr[k];
        out[NY1 + row * 3 + c] = tanhf(acc) * 10.f;
    }
}

// ---------------- launch ----------------
extern "C" void kernel_launch(void* const* d_in, const int* in_sizes, int n_in,
                              void* d_out, int out_size, void* d_ws, size_t ws_size,
                              hipStream_t stream)
{
    (void)in_sizes; (void)n_in; (void)out_size; (void)ws_size;
    const float* x    = (const float*)d_in[0];
    const float* w1   = (const float*)d_in[1];
    const float* bc1  = (const float*)d_in[2];
    const float* w2   = (const float*)d_in[3];
    const float* bc2  = (const float*)d_in[4];
    const float* w3   = (const float*)d_in[5];
    const float* bc3  = (const float*)d_in[6];
    const float* w_ih = (const float*)d_in[7];
    const float* w_hh = (const float*)d_in[8];
    const float* b_ih = (const float*)d_in[9];
    const float* b_hh = (const float*)d_in[10];
    const float* wy1  = (const float*)d_in[11];
    const float* by1  = (const float*)d_in[12];
    const float* wy2  = (const float*)d_in[13];
    const float* by2  = (const float*)d_in[14];
    float* out = (float*)d_out;

    // workspace carve-up (~62 MiB; c2T overlays xT — xT dead after conv1)
    char* wsp = (char*)d_ws;
    auto alloc = [&](size_t bytes) -> char* {
        char* p = wsp; wsp += (bytes + 255) & ~(size_t)255; return p;
    };
    _Float16* wp1  = (_Float16*)alloc((size_t)112 * KP * 2);
    _Float16* wp2  = (_Float16*)alloc((size_t)112 * KP * 2);
    _Float16* wp3  = (_Float16*)alloc((size_t)112 * KP * 2);
    _Float16* wihp = (_Float16*)alloc((size_t)GIN * GIK * 2);
    _Float16* xT   = (_Float16*)alloc((size_t)BCH * INP0 * CIP * 2);       // 17.5 MB
    _Float16* c1T  = (_Float16*)alloc((size_t)BCH * 150 * WD * CIP * 2);   // 16.5 MB
    _Float16* gi   = (_Float16*)alloc((size_t)BCH * TDIM * GIK * 2);       // 14.0 MB
    float*    xw   = (float*)   alloc((size_t)BTOT * TDIM * G3 * 4);
    float*    g    = (float*)   alloc((size_t)BTOT * TDIM * HIDN * 4);
    _Float16* c2T  = xT;   // overlay: conv2 reads c1T, writes into xT's space

    prep_convw<<<(112 * KP + 255) / 256, 256, 0, stream>>>(w1, wp1);
    prep_convw<<<(112 * KP + 255) / 256, 256, 0, stream>>>(w2, wp2);
    prep_convw<<<(112 * KP + 255) / 256, 256, 0, stream>>>(w3, wp3);
    prep_wih<<<dim3((GIK + 255) / 256, GIN), 256, 0, stream>>>(w_ih, wihp);
    init_xw_k<<<(BTOT * TDIM * G3 + 255) / 256, 256, 0, stream>>>(b_ih, xw);

    // conv grids: x-dim padded so (x*BCH) % 8 == 0 (required by the XCD swizzle)
    for (int cb = 0; cb < BTOT; cb += BCH) {
        transpose_x<<<dim3((INP0 + 63) / 64, BCH), 256, 0, stream>>>(
            x + (size_t)cb * 100 * INP0, xT);
        conv_mfma<159, true><<<dim3(78, BCH), 256, 0, stream>>>(xT,  wp1, bc1, c1T);  // 78*4=312
        conv_mfma<150, true><<<dim3(74, BCH), 256, 0, stream>>>(c1T, wp2, bc2, c2T);  // 73->74 pad
        conv_mfma<141, false><<<dim3(70, BCH), 256, 0, stream>>>(c2T, wp3, bc3, gi);  // 69->70 pad
        gemm_mfma<<<dim3(3, 4, 26), 256, 0, stream>>>(gi, wihp, xw + (size_t)cb * TDIM * G3);
    }
    gru_k<<<16, 320, 0, stream>>>(xw, w_hh, b_hh, g);
    heads_k<<<(27200 + 255) / 256, 256, 0, stream>>>(g, wy1, by1, wy2, by2, out);
}

// Round 7
// 1959.854 us; speedup vs baseline: 1.2710x; 1.2710x over previous
//
#include <hip/hip_runtime.h>
#include <math.h>

// ---------------- problem constants ----------------
#define TDIM  100
#define HIDN  100
#define G3    300
#define WD    132
#define KP    1056         // conv K = 10 kh * 104 ci (padded) -> 132 octets
#define NKC   33           // 33 ksteps of 32
#define OCTC  132          // KP/8 (octets 130,131 are pad -> MUST be zero weights)
#define GIK   17440        // padded FEAT -> 545 ksteps of 32, 2180 octets
#define OCTG  2180
#define GIN   320          // padded 3*HID
#define BTOT  16
#define BCH   8            // batches per chunk (ws ~110 MiB, proven in R4)
#define MROW  (BCH * TDIM) // 800 gi rows per chunk
#define INP0  (159 * WD)   // 20988

typedef float    f32x4 __attribute__((ext_vector_type(4)));
typedef _Float16 f16x8 __attribute__((ext_vector_type(8)));
typedef _Float16 f16x4 __attribute__((ext_vector_type(4)));

static __device__ __forceinline__ float sigmoidf_(float x) {
    return 1.f / (1.f + __expf(-x));
}
static __device__ __forceinline__ float bcastf(float v, int l) {
    return __int_as_float(__builtin_amdgcn_readlane(__float_as_int(v), l));
}

// ---- weight prepack: w[co][ci][kh] -> wp2[(o*112+co)*8+j], o=kh*13+ci8, ci=ci8*8+j ----
// CORRECTNESS-CRITICAL: kh<10 guard! o in {130,131} decodes to kh=10 (pad octets);
// without the guard they pick up garbage weights that contaminate every output
// (the R6 bug: y1 passed, y2 failed at 7.09 from exactly this).
__global__ __launch_bounds__(256)
void prep_convw(const float* __restrict__ w, _Float16* __restrict__ wp2)
{
    const int idx = blockIdx.x * 256 + threadIdx.x;
    if (idx >= OCTC * 112) return;
    const int o = idx / 112, co = idx - o * 112;
    const int kh = o / 13, c8 = o - kh * 13;
    f16x8 v;
    #pragma unroll
    for (int j = 0; j < 8; ++j) {
        const int ci = c8 * 8 + j;
        v[j] = (_Float16)((co < 100 && ci < 100 && kh < 10)
                          ? w[(co * 100 + ci) * 10 + kh] : 0.f);
    }
    *(f16x8*)(wp2 + (size_t)idx * 8) = v;
}

// ---- w_ih prepack: [300][17424] fp32 -> wihpO[(o*320+n)*8+j] fp16 (octet layout) ----
__global__ __launch_bounds__(256)
void prep_wih(const float* __restrict__ w_ih, _Float16* __restrict__ wihpO)
{
    const int idx = blockIdx.x * 256 + threadIdx.x;
    if (idx >= GIN * OCTG) return;
    const int n = idx / OCTG, o = idx - n * OCTG;
    f16x8 v;
    #pragma unroll
    for (int j = 0; j < 8; ++j) {
        const int k = o * 8 + j;
        v[j] = (_Float16)((n < G3 && k < 17424) ? w_ih[(size_t)n * 17424 + k] : 0.f);
    }
    *(f16x8*)(wihpO + ((size_t)o * GIN + n) * 8) = v;
}

// ---- x transpose: x[b][ci][p] fp32 -> xT2[b][ci8][p][8] fp16 (pad ci zeroed) ----
__global__ __launch_bounds__(256)
void transpose_x(const float* __restrict__ x, _Float16* __restrict__ xT)
{
    __shared__ __align__(16) _Float16 t[64][120];   // pitch 120 f16 = 240 B (16B-mult)
    const int tid = threadIdx.x;
    const int p0  = blockIdx.x * 64;
    const int b   = blockIdx.y;
    const int pl  = tid & 63;
    const int p   = p0 + pl;
    t[tid >> 2][100 + (tid & 3)] = (_Float16)0.f;   // zero ci pad (finite!)
    const float* xb = x + (size_t)b * 100 * INP0;
    #pragma unroll
    for (int i = 0; i < 25; ++i) {
        const int ci = (tid >> 6) + i * 4;
        const float v = (p < INP0) ? xb[(size_t)ci * INP0 + p] : 0.f;
        t[pl][ci] = (_Float16)v;
    }
    __syncthreads();
    _Float16* xTb = xT + (size_t)b * 13 * INP0 * 8;
    for (int i = tid; i < 13 * 64; i += 256) {
        const int o = i >> 6, pr = i & 63;
        if (p0 + pr < INP0)
            *(uint4*)(xTb + ((size_t)o * INP0 + p0 + pr) * 8) =
                *(const uint4*)&t[pr][o * 8];
    }
}

// ---------------- conv as MFMA GEMM — all staging loads/stores contiguous ----------------
// C[co,p] = bias[co] + sum_k wp[co][k] * act[p+kh*132][ci], octet layouts everywhere.
// Tiles: M=112 (7x16), N=256 (16x16/wave); OUTT -> act2-layout fp16; else giO octet layout.
template<int HIN, bool OUTT>
__global__ __launch_bounds__(256)
void conv_mfma(const _Float16* __restrict__ act,    // [BCH][13][HIN*132][8]
               const _Float16* __restrict__ wp,     // [132][112][8]
               const float*    __restrict__ bias,   // [100]
               _Float16* __restrict__ out)
{
    constexpr int HOUT = HIN - 9;
    constexpr int NP   = HOUT * WD;
    constexpr int INP  = HIN * WD;

    // pool: k-loop As[112][40]+Bs[256][40]=14720 f16; epilogue reuses as [128][112]/[104][136]
    __shared__ __align__(16) _Float16 smem[368 * 40];
    _Float16 (*As)[40] = (_Float16(*)[40])smem;
    _Float16 (*Bs)[40] = (_Float16(*)[40])(smem + 112 * 40);

    // XCD-aware swizzle (gridDim.y==8 -> total%8==0 always)
    const int nbx = gridDim.x;
    int g = blockIdx.y * nbx + blockIdx.x;
    const int per = (nbx * gridDim.y) >> 3;
    g = (g & 7) * per + (g >> 3);
    const int px = g % nbx;
    const int b  = g / nbx;
    const int p0 = px * 256;
    if (p0 >= NP) return;

    const _Float16* act_b = act + (size_t)b * 13 * INP * 8;

    f32x4 acc[7][4] = {};
    const int tid = threadIdx.x;
    const int wv = tid >> 6, ln = tid & 15, lq = (tid & 63) >> 4;
    const int arow = tid >> 2;          // 0..63
    const int run  = tid & 3;           // octet within kstep

    uint4 ar[2], br[4];

    auto load_regs = [&](int kk) {
        const int o  = kk * 4 + run;            // conv octet 0..131
        const int kh = o / 13, c8 = o - kh * 13;
        ar[0] = *(const uint4*)(wp + ((size_t)o * 112 + arow) * 8);
        if (tid < 192)
            ar[1] = *(const uint4*)(wp + ((size_t)o * 112 + 64 + arow) * 8);
        const _Float16* src = act_b + (size_t)c8 * INP * 8;
        const int rbase = p0 + kh * WD + arow;
        #pragma unroll
        for (int i = 0; i < 4; ++i) {
            const int row = min(rbase + i * 64, INP - 1);  // clamp feeds discarded cols only
            br[i] = *(const uint4*)(src + (size_t)row * 8);
        }
    };

    load_regs(0);
    for (int kk = 0; kk < NKC; ++kk) {
        *(uint4*)&As[arow][run * 8] = ar[0];
        if (tid < 192) *(uint4*)&As[64 + arow][run * 8] = ar[1];
        #pragma unroll
        for (int i = 0; i < 4; ++i)
            *(uint4*)&Bs[arow + i * 64][run * 8] = br[i];
        __syncthreads();
        if (kk + 1 < NKC) load_regs(kk + 1);   // contiguous loads overlap MFMA phase
        f16x8 bf[4];
        #pragma unroll
        for (int j = 0; j < 4; ++j)
            bf[j] = *(const f16x8*)&Bs[(wv * 4 + j) * 16 + ln][lq * 8];
        #pragma unroll
        for (int mt = 0; mt < 7; ++mt) {
            const f16x8 af = *(const f16x8*)&As[mt * 16 + ln][lq * 8];
            #pragma unroll
            for (int j = 0; j < 4; ++j)
                acc[mt][j] = __builtin_amdgcn_mfma_f32_16x16x32_f16(af, bf[j], acc[mt][j], 0, 0, 0);
        }
        __syncthreads();
    }

    // ---- LDS-staged epilogue, 2 passes of 128 p-rows; all global stores contiguous ----
    const int wv2 = wv >> 1;
    #pragma unroll
    for (int ph = 0; ph < 2; ++ph) {
        __syncthreads();
        if (wv2 == ph) {
            #pragma unroll
            for (int j = 0; j < 4; ++j) {
                const int pl = (wv & 1) * 64 + j * 16 + ln;   // 0..127
                if (OUTT) {
                    _Float16* row = smem + pl * 112;          // pitch 112 (224 B)
                    #pragma unroll
                    for (int mt = 0; mt < 7; ++mt) {
                        const int co0 = mt * 16 + lq * 4;
                        if (co0 < 104) {
                            f16x4 v;
                            #pragma unroll
                            for (int r = 0; r < 4; ++r) {
                                const int co = co0 + r;
                                v[r] = (_Float16)(acc[mt][j][r] + (co < 100 ? bias[co] : 0.f));
                            }
                            *(f16x4*)(row + co0) = v;
                        }
                    }
                } else {
                    #pragma unroll
                    for (int mt = 0; mt < 7; ++mt) {
                        #pragma unroll
                        for (int r = 0; r < 4; ++r) {
                            const int co = mt * 16 + lq * 4 + r;
                            if (co < 104)
                                smem[co * 136 + pl] =          // pitch 136 (272 B)
                                    (_Float16)(acc[mt][j][r] + (co < 100 ? bias[co] : 0.f));
                        }
                    }
                }
            }
        }
        __syncthreads();
        if (OUTT) {
            // act2 layout: out[b][c8][p][8]
            _Float16* ob = out + (size_t)b * 13 * NP * 8;
            for (int i = tid; i < 13 * 128; i += 256) {
                const int c8 = i >> 7, pr = i & 127;
                const int p = p0 + ph * 128 + pr;
                if (p < NP)
                    *(uint4*)(ob + ((size_t)c8 * NP + p) * 8) =
                        *(const uint4*)(smem + pr * 112 + c8 * 8);
            }
        } else {
            // giO layout: out[(p/8)*MROW + b*100 + r][8]; consecutive lanes (same ol,
            // consecutive r) -> contiguous 16B stores (row-contiguous octet layout)
            for (int i = tid; i < 16 * 100; i += 256) {
                const int ol = i / 100, r = i - ol * 100;
                const int pc = p0 + ph * 128 + ol * 8;
                if (pc < NP)   // NP%8==0 -> all-or-nothing
                    *(uint4*)(out + ((size_t)(pc >> 3) * MROW + b * 100 + r) * 8) =
                        *(const uint4*)(smem + r * 136 + ol * 8);
            }
        }
    }
}

// ---------------- big GEMM: xw += gi @ w_ih^T (octet layouts, 128x128, z=24) ----------------
__global__ __launch_bounds__(256)
void gemm_mfma(const _Float16* __restrict__ A,   // giO [2180][800][8]
               const _Float16* __restrict__ B,   // wihpO [2180][320][8]
               float* __restrict__ C)            // xw rows for this chunk
{
    constexpr int NKG = GIK / 32;    // 545
    constexpr int SEG = 23;          // 24 z-slices

    __shared__ __align__(16) _Float16 As[128][40];
    __shared__ __align__(16) _Float16 Bs[128][40];

    const int tid = threadIdx.x;
    const int n0  = blockIdx.x * 128;
    const int m0  = blockIdx.y * 128;
    const int k00 = blockIdx.z * SEG;
    const int k01 = min(NKG, k00 + SEG);

    const int wv = tid >> 6, ln = tid & 15, lq = (tid & 63) >> 4;
    const int mh = wv >> 1, nh = wv & 1;
    const int grow = tid >> 2, run = tid & 3;

    f32x4 acc[4][4] = {};
    uint4 ar[2], br[2];

    auto load_regs = [&](int kk) {
        const int o = kk * 4 + run;              // octet 0..2179
        #pragma unroll
        for (int i = 0; i < 2; ++i) {
            const int ra = min(m0 + grow + i * 64, MROW - 1);
            const int rb = min(n0 + grow + i * 64, GIN - 1);
            ar[i] = *(const uint4*)(A + ((size_t)o * MROW + ra) * 8);
            br[i] = *(const uint4*)(B + ((size_t)o * GIN + rb) * 8);
        }
    };

    load_regs(k00);
    for (int kk = k00; kk < k01; ++kk) {
        #pragma unroll
        for (int i = 0; i < 2; ++i) {
            *(uint4*)&As[grow + i * 64][run * 8] = ar[i];
            *(uint4*)&Bs[grow + i * 64][run * 8] = br[i];
        }
        __syncthreads();
        if (kk + 1 < k01) load_regs(kk + 1);
        f16x8 af[4], bf[4];
        #pragma unroll
        for (int i = 0; i < 4; ++i) {
            af[i] = *(const f16x8*)&As[mh * 64 + i * 16 + ln][lq * 8];
            bf[i] = *(const f16x8*)&Bs[nh * 64 + i * 16 + ln][lq * 8];
        }
        #pragma unroll
        for (int mt = 0; mt < 4; ++mt)
            #pragma unroll
            for (int nt = 0; nt < 4; ++nt)
                acc[mt][nt] = __builtin_amdgcn_mfma_f32_16x16x32_f16(af[mt], bf[nt], acc[mt][nt], 0, 0, 0);
        __syncthreads();
    }

    #pragma unroll
    for (int mt = 0; mt < 4; ++mt) {
        #pragma unroll
        for (int nt = 0; nt < 4; ++nt) {
            const int n = n0 + nh * 64 + nt * 16 + ln;
            const int mb = m0 + mh * 64 + mt * 16 + lq * 4;
            if (n < G3) {
                #pragma unroll
                for (int rr = 0; rr < 4; ++rr) {
                    const int m = mb + rr;
                    if (m < MROW) atomicAdd(&C[(size_t)m * G3 + n], acc[mt][nt][rr]);
                }
            }
        }
    }
}

// ---------------- xw init: xw[row, g] = b_ih[g] ----------------
__global__ __launch_bounds__(256)
void init_xw_k(const float* __restrict__ b_ih, float* __restrict__ xw)
{
    const int i = blockIdx.x * 256 + threadIdx.x;
    if (i < BTOT * TDIM * G3) xw[i] = b_ih[i % G3];
}

// ---------------- GRU scan (verified structure; prefetch + 4-way acc) ----------------
__global__ __launch_bounds__(320)
void gru_k(const float* __restrict__ xw, const float* __restrict__ w_hh,
           const float* __restrict__ b_hh, float* __restrict__ gout)
{
    __shared__ float h_s[128];
    __shared__ float gh_s[G3];
    __shared__ float xw_s[G3];

    const int tid = threadIdx.x;
    const int b   = blockIdx.x;
    const float* xw_b = xw + (size_t)b * TDIM * G3;

    const int rowc = (tid < G3) ? tid : (G3 - 1);
    const float bh = b_hh[rowc];
    float wreg[HIDN];
    #pragma unroll
    for (int k = 0; k < HIDN; ++k) wreg[k] = w_hh[(size_t)rowc * HIDN + k];

    if (tid < 128) h_s[tid] = 0.f;
    float xr = 0.f;
    if (tid < G3) xr = xw_b[tid];
    __syncthreads();

    const int lane = tid & 63;
    for (int t = 0; t < TDIM; ++t) {
        const float hlo = h_s[lane];          // full-exec snapshot (readlane hazard)
        const float hhi = h_s[64 + lane];
        if (tid < G3) xw_s[tid] = xr;
        float xr_n = 0.f;                      // prefetch next step: hide HBM latency
        if (tid < G3) xr_n = xw_b[(size_t)min(t + 1, TDIM - 1) * G3 + tid];
        float a0 = bh, a1 = 0.f, a2 = 0.f, a3 = 0.f;
        #pragma unroll
        for (int k = 0; k < 64; k += 4) {
            a0 += wreg[k + 0] * bcastf(hlo, k + 0);
            a1 += wreg[k + 1] * bcastf(hlo, k + 1);
            a2 += wreg[k + 2] * bcastf(hlo, k + 2);
            a3 += wreg[k + 3] * bcastf(hlo, k + 3);
        }
        #pragma unroll
        for (int k = 64; k < 100; k += 4) {
            a0 += wreg[k + 0] * bcastf(hhi, k - 64);
            a1 += wreg[k + 1] * bcastf(hhi, k - 63);
            a2 += wreg[k + 2] * bcastf(hhi, k - 62);
            a3 += wreg[k + 3] * bcastf(hhi, k - 61);
        }
        if (tid < G3) gh_s[tid] = (a0 + a1) + (a2 + a3);
        __syncthreads();
        if (tid < HIDN) {
            const float hp = h_s[tid];
            const float r  = sigmoidf_(xw_s[tid]            + gh_s[tid]);
            const float z  = sigmoidf_(xw_s[HIDN + tid]     + gh_s[HIDN + tid]);
            const float n  = tanhf(xw_s[2 * HIDN + tid] + r * gh_s[2 * HIDN + tid]);
            const float hn = (1.f - z) * n + z * hp;
            h_s[tid] = hn;
            gout[((size_t)b * TDIM + t) * HIDN + tid] = hn;
        }
        xr = xr_n;
        __syncthreads();
    }
}

// ---------------- output heads ----------------
__global__ __launch_bounds__(256)
void heads_k(const float* __restrict__ g,
             const float* __restrict__ wy1, const float* __restrict__ by1,
             const float* __restrict__ wy2, const float* __restrict__ by2,
             float* __restrict__ out)
{
    constexpr int NY1 = BTOT * TDIM * 14;
    constexpr int NY2 = BTOT * TDIM * 3;
    const int idx = blockIdx.x * 256 + threadIdx.x;
    if (idx < NY1) {
        const int row = idx / 14, c = idx - row * 14;
        const float* gr = g + (size_t)row * HIDN;
        const float* wr = wy1 + c * HIDN;
        float acc = by1[c];
        for (int k = 0; k < HIDN; ++k) acc += gr[k] * wr[k];
        out[idx] = sigmoidf_(acc);
    } else if (idx < NY1 + NY2) {
        const int j = idx - NY1;
        const int row = j / 3, c = j - row * 3;
        const float* gr = g + (size_t)row * HIDN;
        const float* wr = wy2 + c * HIDN;
        float acc = by2[c];
        for (int k = 0; k < HIDN; ++k) acc += gr[k] * wr[k];
        out[NY1 + row * 3 + c] = tanhf(acc) * 10.f;
    }
}

// ---------------- launch ----------------
extern "C" void kernel_launch(void* const* d_in, const int* in_sizes, int n_in,
                              void* d_out, int out_size, void* d_ws, size_t ws_size,
                              hipStream_t stream)
{
    (void)in_sizes; (void)n_in; (void)out_size; (void)ws_size;
    const float* x    = (const float*)d_in[0];
    const float* w1   = (const float*)d_in[1];
    const float* bc1  = (const float*)d_in[2];
    const float* w2   = (const float*)d_in[3];
    const float* bc2  = (const float*)d_in[4];
    const float* w3   = (const float*)d_in[5];
    const float* bc3  = (const float*)d_in[6];
    const float* w_ih = (const float*)d_in[7];
    const float* w_hh = (const float*)d_in[8];
    const float* b_ih = (const float*)d_in[9];
    const float* b_hh = (const float*)d_in[10];
    const float* wy1  = (const float*)d_in[11];
    const float* by1  = (const float*)d_in[12];
    const float* wy2  = (const float*)d_in[13];
    const float* by2  = (const float*)d_in[14];
    float* out = (float*)d_out;

    // workspace carve-up (~110 MiB; c2T overlays xT2 — dead after conv1)
    char* wsp = (char*)d_ws;
    auto alloc = [&](size_t bytes) -> char* {
        char* p = wsp; wsp += (bytes + 255) & ~(size_t)255; return p;
    };
    _Float16* wp1   = (_Float16*)alloc((size_t)OCTC * 112 * 8 * 2);
    _Float16* wp2   = (_Float16*)alloc((size_t)OCTC * 112 * 8 * 2);
    _Float16* wp3   = (_Float16*)alloc((size_t)OCTC * 112 * 8 * 2);
    _Float16* wihpO = (_Float16*)alloc((size_t)OCTG * GIN * 8 * 2);          // 11.2 MB
    _Float16* xT2   = (_Float16*)alloc((size_t)BCH * 13 * INP0 * 8 * 2);     // 34.9 MB
    _Float16* c1T   = (_Float16*)alloc((size_t)BCH * 13 * (150 * WD) * 8 * 2); // 33.0 MB
    _Float16* giO   = (_Float16*)alloc((size_t)OCTG * MROW * 8 * 2);         // 27.9 MB
    float*    xw    = (float*)   alloc((size_t)BTOT * TDIM * G3 * 4);
    float*    g     = (float*)   alloc((size_t)BTOT * TDIM * HIDN * 4);
    _Float16* c2T   = xT2;   // overlay (31.0 MB needed <= 34.9 MB)

    prep_convw<<<(OCTC * 112 + 255) / 256, 256, 0, stream>>>(w1, wp1);
    prep_convw<<<(OCTC * 112 + 255) / 256, 256, 0, stream>>>(w2, wp2);
    prep_convw<<<(OCTC * 112 + 255) / 256, 256, 0, stream>>>(w3, wp3);
    prep_wih<<<(GIN * OCTG + 255) / 256, 256, 0, stream>>>(w_ih, wihpO);
    init_xw_k<<<(BTOT * TDIM * G3 + 255) / 256, 256, 0, stream>>>(b_ih, xw);

    for (int cb = 0; cb < BTOT; cb += BCH) {
        transpose_x<<<dim3((INP0 + 63) / 64, BCH), 256, 0, stream>>>(
            x + (size_t)cb * 100 * INP0, xT2);
        conv_mfma<159, true ><<<dim3(78, BCH), 256, 0, stream>>>(xT2, wp1, bc1, c1T);
        conv_mfma<150, true ><<<dim3(73, BCH), 256, 0, stream>>>(c1T, wp2, bc2, c2T);
        conv_mfma<141, false><<<dim3(69, BCH), 256, 0, stream>>>(c2T, wp3, bc3, giO);
        gemm_mfma<<<dim3(3, 7, 24), 256, 0, stream>>>(giO, wihpO, xw + (size_t)cb * TDIM * G3);
    }
    gru_k<<<16, 320, 0, stream>>>(xw, w_hh, b_hh, g);
    heads_k<<<(27200 + 255) / 256, 256, 0, stream>>>(g, wy1, by1, wy2, by2, out);
}